// Round 2
// baseline (831.801 us; speedup 1.0000x reference)
//
#include <hip/hip_runtime.h>
#include <math.h>

#define D     512
#define BSZ   16
#define TLEN  16384
#define ROWS  128              // lfb rows per block in k_attn
#define CHUNKS (TLEN / ROWS)   // 128 partials per batch
#define LN_EPS 1e-5f
#define SCALE 22.627416997969522f  // sqrt(512)

typedef float v4 __attribute__((ext_vector_type(4)));

// ---- static scratch: fully rewritten each call before any read ----
__device__ __align__(16) float g_theta[BSZ * D];
__device__ __align__(16) float g_u[BSZ * D];
__device__ __align__(16) float g_pm[BSZ * CHUNKS];
__device__ __align__(16) float g_pl[BSZ * CHUNKS];
__device__ __align__(16) float g_pv[BSZ * CHUNKS * D];
__device__ __align__(16) float g_v[BSZ * D];
__device__ __align__(16) float g_ctx[BSZ * D];
__device__ __align__(16) float g_h[BSZ * D];
__device__ __align__(16) float g_rf[BSZ * 2 * D];    // relu'd feats (nlb input)
__device__ __align__(16) float g_gact[BSZ * 2 * D];

// ---------- A1: theta = x @ W_theta^T + b_theta, weight-stationary over B ----
// grid 16 (32-row W slices), block 256. Thread handles one W row for 2 batches.
__global__ __launch_bounds__(256) void k_theta(const float* __restrict__ x,
                                               const float* __restrict__ w_theta,
                                               const float* __restrict__ b_theta) {
  __shared__ float xs[BSZ][D];
  const int t = threadIdx.x;
  {
    const float4* xg = (const float4*)x;
    float4* xl = (float4*)&xs[0][0];
#pragma unroll
    for (int k = 0; k < 8; ++k) xl[k * 256 + t] = xg[k * 256 + t];
  }
  __syncthreads();
  const int r = t & 31, bg = t >> 5;
  const int row = blockIdx.x * 32 + r;
  const float4* wrow = (const float4*)(w_theta + (size_t)row * D);
  float acc0 = 0.f, acc1 = 0.f;
#pragma unroll 4
  for (int e = 0; e < D / 4; ++e) {
    float4 w = wrow[e];
    const float* p0 = &xs[bg][e * 4];
    const float* p1 = &xs[bg + 8][e * 4];
    acc0 += w.x * p0[0] + w.y * p0[1] + w.z * p0[2] + w.w * p0[3];
    acc1 += w.x * p1[0] + w.y * p1[1] + w.z * p1[2] + w.w * p1[3];
  }
  const float bb = b_theta[row];
  g_theta[bg * D + row] = acc0 + bb;
  g_theta[(bg + 8) * D + row] = acc1 + bb;
}

// ---------- A2: u = scale * theta @ W_phi, weight-stationary over B ----------
// grid 16 (32-col slices of W_phi), block 256.
__global__ __launch_bounds__(256) void k_u(const float* __restrict__ w_phi) {
  __shared__ float th[BSZ][D];
  const int t = threadIdx.x;
  {
    const float4* tg = (const float4*)g_theta;
    float4* tl = (float4*)&th[0][0];
#pragma unroll
    for (int k = 0; k < 8; ++k) tl[k * 256 + t] = tg[k * 256 + t];
  }
  __syncthreads();
  const int ei = t & 31, bg = t >> 5;
  const int e = blockIdx.x * 32 + ei;
  float acc0 = 0.f, acc1 = 0.f;
#pragma unroll 8
  for (int d = 0; d < D; ++d) {
    float w = w_phi[(size_t)d * D + e];
    acc0 += th[bg][d] * w;
    acc1 += th[bg + 8][d] * w;
  }
  g_u[bg * D + e] = acc0 * SCALE;
  g_u[(bg + 8) * D + e] = acc1 * SCALE;
}

// ---------- B: single-pass online-softmax over lfb rows, 2-row unroll -------
__global__ __launch_bounds__(256) void k_attn(const float* __restrict__ lfb) {
  const int b = blockIdx.y, chunk = blockIdx.x;
  const int tid = threadIdx.x, lane = tid & 63, wave = tid >> 6;

  const v4* urow = (const v4*)(g_u + b * D);
  const v4 u0 = urow[lane];
  const v4 u1 = urow[64 + lane];

  float m = -INFINITY, l = 0.f;
  v4 va = {0.f, 0.f, 0.f, 0.f};
  v4 vb = {0.f, 0.f, 0.f, 0.f};

  const float* base = lfb + ((size_t)b * TLEN + (size_t)chunk * ROWS) * D;
  for (int i = 0; i < ROWS / 8; ++i) {
    const v4* r0 = (const v4*)(base + (size_t)(i * 8 + wave * 2) * D);
    const v4* r1 = r0 + (D / 4);
    v4 a0 = __builtin_nontemporal_load(r0 + lane);
    v4 c0 = __builtin_nontemporal_load(r0 + 64 + lane);
    v4 a1 = __builtin_nontemporal_load(r1 + lane);
    v4 c1 = __builtin_nontemporal_load(r1 + 64 + lane);
    v4 p0 = a0 * u0 + c0 * u1;
    v4 p1 = a1 * u0 + c1 * u1;
    float s0 = p0.x + p0.y + p0.z + p0.w;
    float s1 = p1.x + p1.y + p1.z + p1.w;
#pragma unroll
    for (int off = 32; off > 0; off >>= 1) {   // two independent chains overlap
      s0 += __shfl_xor(s0, off);
      s1 += __shfl_xor(s1, off);
    }
    if (s0 > m) {          // wave-uniform: no divergence
      float al = __expf(m - s0);   // first iter: exp(-inf)=0 zeroes init state
      l = l * al + 1.f; va = va * al + a0; vb = vb * al + c0; m = s0;
    } else {
      float w = __expf(s0 - m);
      l += w; va += a0 * w; vb += c0 * w;
    }
    if (s1 > m) {
      float al = __expf(m - s1);
      l = l * al + 1.f; va = va * al + a1; vb = vb * al + c1; m = s1;
    } else {
      float w = __expf(s1 - m);
      l += w; va += a1 * w; vb += c1 * w;
    }
  }

  __shared__ float wm[4], wl[4];
  __shared__ float wv[4][D];
  ((v4*)wv[wave])[lane] = va;
  ((v4*)wv[wave])[64 + lane] = vb;
  if (lane == 0) { wm[wave] = m; wl[wave] = l; }
  __syncthreads();

  const float bm = fmaxf(fmaxf(wm[0], wm[1]), fmaxf(wm[2], wm[3]));
  const float f0 = __expf(wm[0] - bm), f1 = __expf(wm[1] - bm);
  const float f2 = __expf(wm[2] - bm), f3 = __expf(wm[3] - bm);
  const size_t pidx = (size_t)b * CHUNKS + chunk;
#pragma unroll
  for (int k = 0; k < 2; ++k) {
    int p = tid + k * 256;
    g_pv[pidx * D + p] =
        f0 * wv[0][p] + f1 * wv[1][p] + f2 * wv[2][p] + f3 * wv[3][p];
  }
  if (tid == 0) {
    g_pm[pidx] = bm;
    g_pl[pidx] = f0 * wl[0] + f1 * wl[1] + f2 * wl[2] + f3 * wl[3];
  }
}

// ---------- C1: combine partials -> v = softmax-weighted mean row ----------
__global__ __launch_bounds__(256) void k_comb() {
  const int b = blockIdx.x, t = threadIdx.x;
  const float* pm = g_pm + b * CHUNKS;
  const float* pl = g_pl + b * CHUNKS;
  const float* pv = g_pv + (size_t)b * CHUNKS * D;
  float bm = -INFINITY;
  for (int c = 0; c < CHUNKS; ++c) bm = fmaxf(bm, pm[c]);
  float lg = 0.f, a0 = 0.f, a1 = 0.f;
  for (int c = 0; c < CHUNKS; ++c) {
    float f = __expf(pm[c] - bm);
    lg += f * pl[c];
    a0 += f * pv[(size_t)c * D + t];
    a1 += f * pv[(size_t)c * D + t + 256];
  }
  const float inv = 1.f / lg;
  g_v[b * D + t] = a0 * inv;
  g_v[b * D + t + 256] = a1 * inv;
}

// ---------- C2: ctx = W_gi v + b_gi, weight-stationary over B ----------
__global__ __launch_bounds__(256) void k_gi(const float* __restrict__ w_gi,
                                            const float* __restrict__ b_gi) {
  __shared__ float vs[BSZ][D];
  const int t = threadIdx.x;
  {
    const float4* vg = (const float4*)g_v;
    float4* vl = (float4*)&vs[0][0];
#pragma unroll
    for (int k = 0; k < 8; ++k) vl[k * 256 + t] = vg[k * 256 + t];
  }
  __syncthreads();
  const int r = t & 31, bg = t >> 5;
  const int row = blockIdx.x * 32 + r;
  const float4* wrow = (const float4*)(w_gi + (size_t)row * D);
  float acc0 = 0.f, acc1 = 0.f;
#pragma unroll 4
  for (int e = 0; e < D / 4; ++e) {
    float4 w = wrow[e];
    const float* p0 = &vs[bg][e * 4];
    const float* p1 = &vs[bg + 8][e * 4];
    acc0 += w.x * p0[0] + w.y * p0[1] + w.z * p0[2] + w.w * p0[3];
    acc1 += w.x * p1[0] + w.y * p1[1] + w.z * p1[2] + w.w * p1[3];
  }
  const float bb = b_gi[row];
  g_ctx[bg * D + row] = acc0 + bb;
  g_ctx[(bg + 8) * D + row] = acc1 + bb;
}

// ---------- C3: h = relu(LN(ctx)); also rf[:,0:D] = relu(x) ----------
__global__ __launch_bounds__(256) void k_ln(const float* __restrict__ ln_g,
                                            const float* __restrict__ ln_b,
                                            const float* __restrict__ x) {
  __shared__ float rs[4], rq[4];
  const int b = blockIdx.x, t = threadIdx.x;
  const float c0 = g_ctx[b * D + t], c1 = g_ctx[b * D + t + 256];
  float s = c0 + c1, sq = c0 * c0 + c1 * c1;
#pragma unroll
  for (int off = 32; off > 0; off >>= 1) {
    s += __shfl_xor(s, off);
    sq += __shfl_xor(sq, off);
  }
  if ((t & 63) == 0) { rs[t >> 6] = s; rq[t >> 6] = sq; }
  __syncthreads();
  const float mu = (rs[0] + rs[1] + rs[2] + rs[3]) * (1.f / D);
  const float var = (rq[0] + rq[1] + rq[2] + rq[3]) * (1.f / D) - mu * mu;
  const float rstd = rsqrtf(var + LN_EPS);
  g_h[b * D + t] = fmaxf((c0 - mu) * rstd * ln_g[t] + ln_b[t], 0.f);
  g_h[b * D + t + 256] =
      fmaxf((c1 - mu) * rstd * ln_g[t + 256] + ln_b[t + 256], 0.f);
  g_rf[b * 2 * D + t] = fmaxf(x[b * D + t], 0.f);
  g_rf[b * 2 * D + t + 256] = fmaxf(x[b * D + t + 256], 0.f);
}

// ---------- C4: rf[:,D:2D] = relu(W_fc h + b_fc + x), weight-stationary ----
__global__ __launch_bounds__(256) void k_fc(const float* __restrict__ w_fc,
                                            const float* __restrict__ b_fc,
                                            const float* __restrict__ x) {
  __shared__ float hs[BSZ][D];
  const int t = threadIdx.x;
  {
    const float4* hg = (const float4*)g_h;
    float4* hl = (float4*)&hs[0][0];
#pragma unroll
    for (int k = 0; k < 8; ++k) hl[k * 256 + t] = hg[k * 256 + t];
  }
  __syncthreads();
  const int r = t & 31, bg = t >> 5;
  const int row = blockIdx.x * 32 + r;
  const float4* wrow = (const float4*)(w_fc + (size_t)row * D);
  float acc0 = 0.f, acc1 = 0.f;
#pragma unroll 4
  for (int e = 0; e < D / 4; ++e) {
    float4 w = wrow[e];
    const float* p0 = &hs[bg][e * 4];
    const float* p1 = &hs[bg + 8][e * 4];
    acc0 += w.x * p0[0] + w.y * p0[1] + w.z * p0[2] + w.w * p0[3];
    acc1 += w.x * p1[0] + w.y * p1[1] + w.z * p1[2] + w.w * p1[3];
  }
  const float bb = b_fc[row];
  g_rf[bg * 2 * D + D + row] = fmaxf(acc0 + bb + x[bg * D + row], 0.f);
  g_rf[(bg + 8) * 2 * D + D + row] =
      fmaxf(acc1 + bb + x[(bg + 8) * D + row], 0.f);
}

// ---------- C5: g = relu(W_nlb rf + b_nlb), weight-stationary over B -------
// grid 32 (32-row slices of the 1024-row W_nlb).
__global__ __launch_bounds__(256) void k_nlb(const float* __restrict__ w_nlb,
                                             const float* __restrict__ b_nlb) {
  __shared__ float fs[BSZ][2 * D];
  const int t = threadIdx.x;
  {
    const float4* fg = (const float4*)g_rf;
    float4* fl = (float4*)&fs[0][0];
#pragma unroll
    for (int k = 0; k < 16; ++k) fl[k * 256 + t] = fg[k * 256 + t];
  }
  __syncthreads();
  const int r = t & 31, bg = t >> 5;
  const int row = blockIdx.x * 32 + r;
  const float4* wrow = (const float4*)(w_nlb + (size_t)row * 2 * D);
  float acc0 = 0.f, acc1 = 0.f;
#pragma unroll 4
  for (int e = 0; e < 2 * D / 4; ++e) {
    float4 w = wrow[e];
    const float* p0 = &fs[bg][e * 4];
    const float* p1 = &fs[bg + 8][e * 4];
    acc0 += w.x * p0[0] + w.y * p0[1] + w.z * p0[2] + w.w * p0[3];
    acc1 += w.x * p1[0] + w.y * p1[1] + w.z * p1[2] + w.w * p1[3];
  }
  const float bb = b_nlb[row];
  g_gact[bg * 2 * D + row] = fmaxf(acc0 + bb, 0.f);
  g_gact[(bg + 8) * 2 * D + row] = fmaxf(acc1 + bb, 0.f);
}

// ---------- C6: preds ----------
__global__ __launch_bounds__(256) void k_pred(const float* __restrict__ w1,
                                              const float* __restrict__ b1,
                                              const float* __restrict__ w2,
                                              const float* __restrict__ b2,
                                              float* __restrict__ out) {
  __shared__ float rs[4], rq[4];
  const int b = blockIdx.x, t = threadIdx.x;
  const float* gb = g_gact + (size_t)b * 2 * D;
  float p1 = gb[t] * w1[t] + gb[t + 256] * w1[t + 256];
  float p2 = gb[D + t] * w2[t] + gb[D + t + 256] * w2[t + 256];
#pragma unroll
  for (int off = 32; off > 0; off >>= 1) {
    p1 += __shfl_xor(p1, off);
    p2 += __shfl_xor(p2, off);
  }
  if ((t & 63) == 0) { rs[t >> 6] = p1; rq[t >> 6] = p2; }
  __syncthreads();
  if (t == 0) {
    out[b * 2 + 0] = rs[0] + rs[1] + rs[2] + rs[3] + b1[0];
    out[b * 2 + 1] = rq[0] + rq[1] + rq[2] + rq[3] + b2[0];
  }
}

extern "C" void kernel_launch(void* const* d_in, const int* in_sizes, int n_in,
                              void* d_out, int out_size, void* d_ws,
                              size_t ws_size, hipStream_t stream) {
  const float* x       = (const float*)d_in[0];
  const float* lfb     = (const float*)d_in[1];
  const float* w_theta = (const float*)d_in[2];
  const float* b_theta = (const float*)d_in[3];
  const float* w_phi   = (const float*)d_in[4];
  // d_in[5] = b_phi: per-batch constant added to scores -> cancels in softmax
  const float* w_gi    = (const float*)d_in[6];
  const float* b_gi    = (const float*)d_in[7];
  const float* ln_g    = (const float*)d_in[8];
  const float* ln_b    = (const float*)d_in[9];
  const float* w_fc    = (const float*)d_in[10];
  const float* b_fc    = (const float*)d_in[11];
  const float* w_nlb   = (const float*)d_in[12];
  const float* b_nlb   = (const float*)d_in[13];
  const float* w1      = (const float*)d_in[14];
  const float* b1      = (const float*)d_in[15];
  const float* w2      = (const float*)d_in[16];
  const float* b2      = (const float*)d_in[17];
  float* out = (float*)d_out;

  k_theta<<<16, 256, 0, stream>>>(x, w_theta, b_theta);
  k_u<<<16, 256, 0, stream>>>(w_phi);
  k_attn<<<dim3(CHUNKS, BSZ), 256, 0, stream>>>(lfb);
  k_comb<<<BSZ, 256, 0, stream>>>();
  k_gi<<<16, 256, 0, stream>>>(w_gi, b_gi);
  k_ln<<<BSZ, 256, 0, stream>>>(ln_g, ln_b, x);
  k_fc<<<16, 256, 0, stream>>>(w_fc, b_fc, x);
  k_nlb<<<32, 256, 0, stream>>>(w_nlb, b_nlb);
  k_pred<<<BSZ, 256, 0, stream>>>(w1, b1, w2, b2, out);
}